// Round 2
// baseline (150.360 us; speedup 1.0000x reference)
//
#include <hip/hip_runtime.h>

// Problem constants (B, C, CI, H, W) = (4, 256, 128, 64, 64)
constexpr int kB  = 4;
constexpr int kC  = 256;
constexpr int kCI = 128;
constexpr int kN  = 64 * 64;  // 4096

// ---------------------------------------------------------------------------
// Algebraic collapse (no gram, no pairwise):
//   Phi = phi_w*X, G2 = g_w*X                (CI x N each; stacked as PG)
//   T   = Phic*G2^T = Phi*G2^T - rsPhi*rsG2^T/N     (CI x CI per batch)
//   W2t = out_w * T^T ; Mt = W2t * theta_wc ; beta = W2t*theta_bc + out_b
//   out[b,o,n] = x[b,o,n] + sum_c Mt[b,o,c]*x[b,c,n] + beta[b,o]
//
// ROUND-11 (kill the PGh round-trip; 6 kernels -> 4):
//   - pgt_mfma: per 64-col n-slice, compute full 256-row PG tile via MFMA,
//     quantize into LDS (never to global), run T-phase MFMA from LDS,
//     atomicAdd into T.  Eliminates PGh (8.4 MB W + 16.8 MB R) and the
//     second xT read (8.4 MB); one less launch.  Weights pre-cast to bf16
//     once (PGWh) in xt_fused -> staging is pure uint4 copies.
//   - wm_kernel: w2t + mt + beta in one kernel (W2row held in LDS; no W2t
//     global round-trip, one less launch).
//   Numerics: same f2b of same fp32 accumulators everywhere; only the fp32
//   atomic sum order in T changes (R10 already validated T atomics).
// ---------------------------------------------------------------------------

typedef __attribute__((ext_vector_type(8))) short bf16x8;   // 8 bf16 = 4 VGPR
typedef __attribute__((ext_vector_type(4))) float f32x4;

__device__ inline ushort f2b(float f) {  // fp32 -> bf16, round-nearest-even
    unsigned u = __float_as_uint(f);
    return (ushort)((u + 0x7FFF + ((u >> 16) & 1)) >> 16);
}
__device__ inline float b2f(ushort u) { return __uint_as_float((unsigned)u << 16); }

// ws layout (float units)
constexpr long kOffTwcT = 0;                                  // 32768
constexpr long kOffTbc  = kOffTwcT + kC * kCI;                // 128
constexpr long kOffRs   = kOffTbc + kCI;                      // 1024
constexpr long kOffT    = kOffRs + kB * kC;                   // kB*kCI*kCI = 65536
constexpr long kOffBeta = kOffT + kB * kCI * kCI;             // 1024
constexpr long kOffPGW  = kOffBeta + kB * kC;                 // bf16: 256*256 ushorts
constexpr long kOffMtH  = kOffPGW + (long)kC * kC / 2;        // bf16: kB*kC*kC ushorts
constexpr long kOffXT   = kOffMtH + (long)kB * kC * kC / 2;   // bf16: kB*kN*kC ushorts

// ---- fused: xT transpose | centerw | T zero | PGW bf16 cast ---------------
// grid (64, 5, 4). y<4: xt tile. y==4: 256 blocks zero T + cast one weight
// row to bf16; first 4 also do centerw (+ tbc) + rs zero.
__global__ void __launch_bounds__(256, 4)
xt_fused(const float* __restrict__ x, ushort* __restrict__ xT,
         const float* __restrict__ theta_w, const float* __restrict__ theta_b,
         const float* __restrict__ phi_w, const float* __restrict__ g_w,
         float* __restrict__ twcT, float* __restrict__ tbc,
         float* __restrict__ rs, float* __restrict__ T,
         ushort* __restrict__ PGWh) {
    __shared__ __align__(16) float smem[128 * 65];  // union: Ls / ft
    int t = threadIdx.x;
    if (blockIdx.y == 4) {
        int idx = blockIdx.z * 64 + blockIdx.x;  // 0..255
        T[(long)idx * 256 + t] = 0.f;            // zero T (consumed by atomics)
        {   // PGWh row idx = bf16([phi_w; g_w][idx][:])
            const float* src = idx < kCI ? phi_w + (long)idx * kC
                                         : g_w + (long)(idx - kCI) * kC;
            if (t < 64) {
                float4 v = *(const float4*)(src + 4 * t);
                ushort4 u = {f2b(v.x), f2b(v.y), f2b(v.z), f2b(v.w)};
                *(ushort4*)(PGWh + (long)idx * kC + 4 * t) = u;
            }
        }
        if (idx >= 4) return;
        // ---- centerw for column block idx ----
        __shared__ float part[64][4];
        __shared__ float meanv[64];
        __shared__ float smr[128];
        float (*Ls)[65] = (float(*)[65])smem;
        int blk = idx, c0 = blk * 64;
        rs[blk * 256 + t] = 0.f;  // zero rs (consumed by pgt's atomics)
#pragma unroll
        for (int it = 0; it < 8; it++) {  // stage theta_w[0:128][c0:c0+64]
            int l = t + 256 * it;
            int k = l >> 4, c4 = (l & 15) * 4;
            float4 v = *(const float4*)(theta_w + (long)k * kC + c0 + c4);
            Ls[k][c4 + 0] = v.x; Ls[k][c4 + 1] = v.y;
            Ls[k][c4 + 2] = v.z; Ls[k][c4 + 3] = v.w;
        }
        __syncthreads();
        {   // column means: 4 threads per column
            int c = t >> 2, q = t & 3;
            float s = 0.f;
#pragma unroll
            for (int k = 0; k < 32; k++) s += Ls[q * 32 + k][c];
            part[c][q] = s;
        }
        __syncthreads();
        if (t < 64)
            meanv[t] = (part[t][0] + part[t][1] + part[t][2] + part[t][3]) * (1.f / kCI);
        __syncthreads();
        {   // twcT[c][k] = theta_w[k][c] - mean[c]
            int c = t >> 2, ks = (t & 3) * 32;
            float* dst = twcT + (long)(c0 + c) * kCI + ks;
            float m = meanv[c];
#pragma unroll
            for (int k = 0; k < 32; k++) dst[k] = Ls[ks + k][c] - m;
        }
        if (blk == 0) {  // tbc = theta_b - mean(theta_b)
            if (t < 128) smr[t] = theta_b[t];
            __syncthreads();
            for (int st = 64; st > 0; st >>= 1) {
                if (t < st) smr[t] += smr[t + st];
                __syncthreads();
            }
            float bmean = smr[0] * (1.f / kCI);
            if (t < 128) tbc[t] = theta_b[t] - bmean;
        }
        return;
    }
    // ---- xt: xT[b][n][c] (bf16) = x[b][c][n] ----
    int b = blockIdx.z;
    int n0 = blockIdx.x * 64, c0 = blockIdx.y * 64;
    float (*ft)[66] = (float(*)[66])smem;  // 64*66 = 4224 floats
    const float* xb = x + (long)b * kC * kN;
#pragma unroll
    for (int i = 0; i < 4; i++) {
        int l = t + 256 * i;
        int row = l >> 4, col4 = (l & 15) * 4;  // row = c index, col = n
        float4 v = *(const float4*)(xb + (long)(c0 + row) * kN + n0 + col4);
        ft[row][col4 + 0] = v.x; ft[row][col4 + 1] = v.y;
        ft[row][col4 + 2] = v.z; ft[row][col4 + 3] = v.w;
    }
    __syncthreads();
    {   // write: thread t -> n-row (t>>2), 16-c segment ((t&3)*16)
        int n = t >> 2, cs = (t & 3) * 16;
        unsigned w[8];
#pragma unroll
        for (int j = 0; j < 8; j++) {
            ushort lo = f2b(ft[cs + 2 * j][n]);
            ushort hi = f2b(ft[cs + 2 * j + 1][n]);
            w[j] = (unsigned)lo | ((unsigned)hi << 16);
        }
        ushort* dst = xT + ((long)b * kN + n0 + n) * kC + c0 + cs;
        ((uint4*)dst)[0] = make_uint4(w[0], w[1], w[2], w[3]);
        ((uint4*)dst)[1] = make_uint4(w[4], w[5], w[6], w[7]);
    }
}

// ---- fused PG + T: per 64-col n-slice ------------------------------------
// Phase 1: PG[0:256][n0:n0+64] = PGW x X  (MFMA), quantize -> LDS, rowsums.
// Phase 2: T += Phi_tile * G2_tile^T (K=64) from LDS, atomicAdd into T.
// 4 waves; wave w owns PG rows 64w..64w+63 (phase 1), T rows 32w..32w+31
// (phase 2).  LDS: Ws 20K + Xs 5K + PGs 36K = 61K -> 2 blocks/CU.
__global__ void __launch_bounds__(256, 2)
pgt_mfma(const ushort* __restrict__ PGWh, const ushort* __restrict__ xT,
         float* __restrict__ rs, float* __restrict__ T) {
    int b = blockIdx.z;
    int n0 = blockIdx.x * 64;
    __shared__ ushort Ws[256 * 40];   // [row][k], stride 40 ushorts (80 B)
    __shared__ ushort Xs[64 * 40];
    __shared__ ushort PGs[256 * 72];  // [row][n-local], stride 72 (144 B)
    int t = threadIdx.x;
    int w = t >> 6, lane = t & 63, q = lane >> 4, ln = lane & 15;
    f32x4 acc[4][4];
#pragma unroll
    for (int i = 0; i < 4; i++)
#pragma unroll
        for (int j = 0; j < 4; j++) acc[i][j] = 0.f;
    const ushort* xTb = xT + ((long)b * kN + n0) * kC;
    for (int kc = 0; kc < kC; kc += 32) {
        __syncthreads();
#pragma unroll
        for (int it = 0; it < 4; it++) {  // W: 256 rows x 32 k (bf16 copy)
            int l = t + 256 * it;
            int row = l >> 2, seg = l & 3;
            *(uint4*)&Ws[row * 40 + seg * 8] =
                *(const uint4*)(PGWh + (long)row * kC + kc + seg * 8);
        }
        {   // X: 64 rows x 32 k (bf16 copy)
            int row = t >> 2, seg = t & 3;
            *(uint4*)&Xs[row * 40 + seg * 8] =
                *(const uint4*)(xTb + (long)row * kC + kc + seg * 8);
        }
        __syncthreads();
        bf16x8 a[4], bb[4];
#pragma unroll
        for (int mt = 0; mt < 4; mt++)
            a[mt] = *(const bf16x8*)&Ws[(64 * w + 16 * mt + ln) * 40 + q * 8];
#pragma unroll
        for (int nt = 0; nt < 4; nt++)
            bb[nt] = *(const bf16x8*)&Xs[(16 * nt + ln) * 40 + q * 8];
#pragma unroll
        for (int mt = 0; mt < 4; mt++)
#pragma unroll
            for (int nt = 0; nt < 4; nt++)
                acc[mt][nt] = __builtin_amdgcn_mfma_f32_16x16x32_bf16(
                    a[mt], bb[nt], acc[mt][nt], 0, 0, 0);
    }
    // quantize -> PGs, rowsums from the SAME quantized values
    float rpart[4][4] = {};
#pragma unroll
    for (int mt = 0; mt < 4; mt++)
#pragma unroll
        for (int nt = 0; nt < 4; nt++)
#pragma unroll
            for (int i = 0; i < 4; i++) {
                int row = 64 * w + 16 * mt + 4 * q + i;
                int col = 16 * nt + ln;
                ushort st = f2b(acc[mt][nt][i]);
                PGs[row * 72 + col] = st;
                rpart[mt][i] += b2f(st);
            }
#pragma unroll
    for (int mt = 0; mt < 4; mt++)
#pragma unroll
        for (int i = 0; i < 4; i++) {
            float v = rpart[mt][i];
            v += __shfl_xor(v, 1);
            v += __shfl_xor(v, 2);
            v += __shfl_xor(v, 4);
            v += __shfl_xor(v, 8);
            if (ln == 0)
                atomicAdd(rs + b * kC + 64 * w + 16 * mt + 4 * q + i, v);
        }
    __syncthreads();
    // ---- T phase: T[c][cp] += sum_n Phi_q[c][n] * G2_q[cp][n], K=64 ------
    f32x4 acc2[2][8];
#pragma unroll
    for (int i = 0; i < 2; i++)
#pragma unroll
        for (int j = 0; j < 8; j++) acc2[i][j] = 0.f;
#pragma unroll
    for (int kk = 0; kk < 64; kk += 32) {
        bf16x8 a2[2], b2[8];
#pragma unroll
        for (int mt = 0; mt < 2; mt++)
            a2[mt] = *(const bf16x8*)&PGs[(32 * w + 16 * mt + ln) * 72 + kk + q * 8];
#pragma unroll
        for (int nt = 0; nt < 8; nt++)
            b2[nt] = *(const bf16x8*)&PGs[(128 + 16 * nt + ln) * 72 + kk + q * 8];
#pragma unroll
        for (int mt = 0; mt < 2; mt++)
#pragma unroll
            for (int nt = 0; nt < 8; nt++)
                acc2[mt][nt] = __builtin_amdgcn_mfma_f32_16x16x32_bf16(
                    a2[mt], b2[nt], acc2[mt][nt], 0, 0, 0);
    }
    float* Tb = T + (long)b * kCI * kCI;
#pragma unroll
    for (int mt = 0; mt < 2; mt++)
#pragma unroll
        for (int nt = 0; nt < 8; nt++)
#pragma unroll
            for (int i = 0; i < 4; i++) {
                int c  = 32 * w + 16 * mt + 4 * q + i;
                int cp = 16 * nt + ln;
                atomicAdd(&Tb[(long)c * kCI + cp], acc2[mt][nt][i]);
            }
}

// ---- fused W2t + Mt + beta ------------------------------------------------
// Phase A: W2row[m][j] = sum_cp out_w[m0+m][cp] * (T[j][cp] - rank1) -> LDS.
// Phase B: Mt[m][n] (bf16) = sum_j W2row[m][j] * twcT[n0+n][j].
// beta[m] = out_b[m] + sum_j tbc[j]*W2row[m][j]  (blocks with n0==0).
__global__ void __launch_bounds__(256, 2)
wm_kernel(const float* __restrict__ out_w, const float* __restrict__ T,
          const float* __restrict__ rs, const float* __restrict__ twcT,
          const float* __restrict__ tbc, const float* __restrict__ out_b,
          ushort* __restrict__ Mth, float* __restrict__ beta) {
    int b = blockIdx.z;
    int m0 = blockIdx.y * 64, n0 = blockIdx.x * 64;
    const float* Tb = T + (long)b * kCI * kCI;
    __shared__ __align__(16) float As[16][68];    // 16 k x 64 stage (A / B2)
    __shared__ __align__(16) float Bs[16][132];   // 16 k x 128 stage (Tc rows)
    __shared__ __align__(16) float W2s[128][68];  // W2row^T: [j][m]
    int t = threadIdx.x;
    int tr = t >> 4, tc = t & 15;  // phase A: rows 4*tr.., cols 8*tc..
    float accA[4][8] = {};
    for (int c0 = 0; c0 < kCI; c0 += 16) {
        __syncthreads();
        {   // out_w[m0:m0+64][c0:c0+16] -> As[c][r]
            int r = t >> 2, c4 = (t & 3) * 4;
            float4 va = *(const float4*)(out_w + (long)(m0 + r) * kCI + c0 + c4);
            As[c4 + 0][r] = va.x; As[c4 + 1][r] = va.y;
            As[c4 + 2][r] = va.z; As[c4 + 3][r] = va.w;
        }
#pragma unroll
        for (int it = 0; it < 2; it++) {  // Tc[0:128][c0:c0+16] -> Bs[c][j]
            int l = t + 256 * it;
            int r = l >> 2, c4 = (l & 3) * 4;
            float4 vb = *(const float4*)(Tb + (long)r * kCI + c0 + c4);
            float rp = rs[b * kC + r] * (1.f / kN);
            const float* rg = rs + b * kC + kCI + c0 + c4;
            vb.x -= rp * rg[0]; vb.y -= rp * rg[1];
            vb.z -= rp * rg[2]; vb.w -= rp * rg[3];
            Bs[c4 + 0][r] = vb.x; Bs[c4 + 1][r] = vb.y;
            Bs[c4 + 2][r] = vb.z; Bs[c4 + 3][r] = vb.w;
        }
        __syncthreads();
#pragma unroll
        for (int k = 0; k < 16; k++) {
            float4 a = *(const float4*)&As[k][4 * tr];
            float4 b0 = *(const float4*)&Bs[k][8 * tc];
            float4 b1 = *(const float4*)&Bs[k][8 * tc + 4];
            float av[4] = {a.x, a.y, a.z, a.w};
            float bw[8] = {b0.x, b0.y, b0.z, b0.w, b1.x, b1.y, b1.z, b1.w};
#pragma unroll
            for (int i = 0; i < 4; i++)
#pragma unroll
                for (int j = 0; j < 8; j++) accA[i][j] += av[i] * bw[j];
        }
    }
    __syncthreads();
#pragma unroll
    for (int i = 0; i < 4; i++)
#pragma unroll
        for (int j = 0; j < 8; j++) W2s[8 * tc + j][4 * tr + i] = accA[i][j];
    __syncthreads();
    if (blockIdx.x == 0 && t < 64) {  // beta
        float s = out_b[m0 + t];
#pragma unroll 8
        for (int j = 0; j < kCI; j++) s += tbc[j] * W2s[j][t];
        beta[b * kC + m0 + t] = s;
    }
    // ---- phase B ----
    int ty = t >> 4, tx = t & 15;
    float accB[4][4] = {};
    for (int j0 = 0; j0 < kCI; j0 += 16) {
        __syncthreads();
        {   // twcT[n0:n0+64][j0:j0+16] -> As[j][n]  (reuse As)
            int r = t >> 2, c4 = (t & 3) * 4;
            float4 vb = *(const float4*)(twcT + (long)(n0 + r) * kCI + j0 + c4);
            As[c4 + 0][r] = vb.x; As[c4 + 1][r] = vb.y;
            As[c4 + 2][r] = vb.z; As[c4 + 3][r] = vb.w;
        }
        __syncthreads();
#pragma unroll
        for (int k = 0; k < 16; k++) {
            float4 a = *(const float4*)&W2s[j0 + k][4 * ty];
            float4 bv = *(const float4*)&As[k][4 * tx];
            float av[4] = {a.x, a.y, a.z, a.w};
            float bw[4] = {bv.x, bv.y, bv.z, bv.w};
#pragma unroll
            for (int i = 0; i < 4; i++)
#pragma unroll
                for (int j = 0; j < 4; j++) accB[i][j] += av[i] * bw[j];
        }
    }
    ushort* Cb = Mth + (long)b * kC * kC;
#pragma unroll
    for (int i = 0; i < 4; i++) {
        ushort4 u = {f2b(accB[i][0]), f2b(accB[i][1]), f2b(accB[i][2]), f2b(accB[i][3])};
        *(ushort4*)(Cb + (long)(m0 + 4 * ty + i) * kC + n0 + 4 * tx) = u;
    }
}

// ---- out = x + Mt(bf16) x X(bf16) + beta  via MFMA ------------------------
// 128(o) x 128(n) tile; residual from fp32 x (coalesced: col = ln-contig).
__global__ void __launch_bounds__(256, 2)
final_mfma(const float* __restrict__ x, const ushort* __restrict__ Mth,
           const ushort* __restrict__ xT, const float* __restrict__ beta,
           float* __restrict__ out) {
    int b = blockIdx.z;
    int o0 = blockIdx.y * 128, n0 = blockIdx.x * 128;
    const ushort* Mbh = Mth + (long)b * kC * kC;
    __shared__ ushort Ws[128 * 40];
    __shared__ ushort Xs[128 * 40];
    int t = threadIdx.x;
    int w = t >> 6, lane = t & 63, q = lane >> 4, ln = lane & 15;
    f32x4 acc[2][8];
#pragma unroll
    for (int i = 0; i < 2; i++)
#pragma unroll
        for (int j = 0; j < 8; j++) acc[i][j] = 0.f;
    const ushort* xTb = xT + ((long)b * kN + n0) * kC;
    for (int kc = 0; kc < kC; kc += 32) {
        __syncthreads();
#pragma unroll
        for (int it = 0; it < 2; it++) {  // Mt: 128 rows x 32 k (bf16 copy)
            int l = t + 256 * it;
            int row = l >> 2, seg = l & 3;
            uint4 v = *(const uint4*)(Mbh + (long)(o0 + row) * kC + kc + seg * 8);
            *(uint4*)&Ws[row * 40 + seg * 8] = v;
        }
#pragma unroll
        for (int it = 0; it < 2; it++) {  // X: 128 rows x 32 k (bf16 copy)
            int l = t + 256 * it;
            int row = l >> 2, seg = l & 3;
            uint4 v = *(const uint4*)(xTb + (long)row * kC + kc + seg * 8);
            *(uint4*)&Xs[row * 40 + seg * 8] = v;
        }
        __syncthreads();
        bf16x8 a[2], bb[8];
#pragma unroll
        for (int mt = 0; mt < 2; mt++)
            a[mt] = *(const bf16x8*)&Ws[(32 * w + 16 * mt + ln) * 40 + q * 8];
#pragma unroll
        for (int nt = 0; nt < 8; nt++)
            bb[nt] = *(const bf16x8*)&Xs[(16 * nt + ln) * 40 + q * 8];
#pragma unroll
        for (int mt = 0; mt < 2; mt++)
#pragma unroll
            for (int nt = 0; nt < 8; nt++)
                acc[mt][nt] = __builtin_amdgcn_mfma_f32_16x16x32_bf16(
                    a[mt], bb[nt], acc[mt][nt], 0, 0, 0);
    }
    const float* xb = x + (long)b * kC * kN;
    float* ob = out + (long)b * kC * kN;
#pragma unroll
    for (int mt = 0; mt < 2; mt++)
#pragma unroll
        for (int nt = 0; nt < 8; nt++)
#pragma unroll
            for (int i = 0; i < 4; i++) {
                int row = o0 + 32 * w + 16 * mt + 4 * q + i;
                int col = n0 + 16 * nt + ln;
                long idx = (long)row * kN + col;
                ob[idx] = acc[mt][nt][i] + xb[idx] + beta[b * kC + row];
            }
}

extern "C" void kernel_launch(void* const* d_in, const int* in_sizes, int n_in,
                              void* d_out, int out_size, void* d_ws, size_t ws_size,
                              hipStream_t stream) {
    const float* x       = (const float*)d_in[0];
    const float* g_w     = (const float*)d_in[1];
    // d_in[2] = g_b   : cancelled (rows of Phic sum to 0)
    const float* theta_w = (const float*)d_in[3];
    const float* theta_b = (const float*)d_in[4];
    const float* phi_w   = (const float*)d_in[5];
    // d_in[6] = phi_b : cancelled by spatial centering
    const float* out_w   = (const float*)d_in[7];
    const float* out_b   = (const float*)d_in[8];
    float* out = (float*)d_out;
    float* ws  = (float*)d_ws;  // needs ~18 MB

    float*  twcT = ws + kOffTwcT;
    float*  tbc  = ws + kOffTbc;
    float*  rs   = ws + kOffRs;
    float*  T    = ws + kOffT;
    float*  beta = ws + kOffBeta;
    ushort* PGWh = (ushort*)(ws + kOffPGW);
    ushort* Mth  = (ushort*)(ws + kOffMtH);
    ushort* xT   = (ushort*)(ws + kOffXT);

    // xT + centerw (twcT/tbc, rs zero) + T zero + PGW bf16 cast, one launch
    xt_fused<<<dim3(kN / 64, 5, kB), 256, 0, stream>>>(
        x, xT, theta_w, theta_b, phi_w, g_w, twcT, tbc, rs, T, PGWh);
    // PG tile in LDS -> T atomic accumulate (PGh never materialized)
    pgt_mfma<<<dim3(kN / 64, 1, kB), 256, 0, stream>>>(PGWh, xT, rs, T);
    // W2t (LDS) -> Mt (bf16) + beta, one kernel
    wm_kernel<<<dim3(4, 4, kB), 256, 0, stream>>>(out_w, T, rs, twcT, tbc,
                                                  out_b, Mth, beta);
    // out = x + Mt * X + beta       (fp32 residual, coalesced)
    final_mfma<<<dim3(kN / 128, 2, kB), 256, 0, stream>>>(x, Mth, xT, beta, out);
}

// Round 3
// 138.461 us; speedup vs baseline: 1.0859x; 1.0859x over previous
//
#include <hip/hip_runtime.h>

// Problem constants (B, C, CI, H, W) = (4, 256, 128, 64, 64)
constexpr int kB  = 4;
constexpr int kC  = 256;
constexpr int kCI = 128;
constexpr int kN  = 64 * 64;  // 4096

// ---------------------------------------------------------------------------
// Algebraic collapse (no gram, no pairwise):
//   Phi = phi_w*X, G2 = g_w*X                (CI x N each; stacked as PG)
//   T   = Phic*G2^T = Phi*G2^T - rsPhi*rsG2^T/N     (CI x CI per batch)
//   W2t = out_w * T^T ; Mt = W2t * theta_wc ; beta = W2t*theta_bc + out_b
//   out[b,o,n] = x[b,o,n] + sum_c Mt[b,o,c]*x[b,c,n] + beta[b,o]
//
// ROUND-12 (revert R11's pgt fusion — it cost +11 us from 64-wide tiles,
// 4.2M contended T-atomics and 2-blk/CU occupancy; PGh round-trip is the
// cheaper design).  R10 structure + two proven pieces kept from R11:
//   - wm_kernel: w2t+mt+beta in one kernel (W2row in LDS, no W2t global
//     round-trip; verified passing in R11)
//   - PGWh: weights pre-cast to bf16 once in xt_fused; pg_mfma W staging
//     becomes a pure uint4 copy (halves its weight L2 traffic, kills f2b)
//   5 launches: xt_fused, pg_mfma, tsplit_mfma, wm_kernel, final_mfma.
// ---------------------------------------------------------------------------

constexpr int kSplits = 16;
constexpr int kSliceN = kN / kSplits;  // 256

typedef __attribute__((ext_vector_type(8))) short bf16x8;   // 8 bf16 = 4 VGPR
typedef __attribute__((ext_vector_type(4))) float f32x4;

__device__ inline ushort f2b(float f) {  // fp32 -> bf16, round-nearest-even
    unsigned u = __float_as_uint(f);
    return (ushort)((u + 0x7FFF + ((u >> 16) & 1)) >> 16);
}
__device__ inline float b2f(ushort u) { return __uint_as_float((unsigned)u << 16); }

// ws layout (float units)
constexpr long kOffTwcT = 0;                                  // 32768
constexpr long kOffTbc  = kOffTwcT + kC * kCI;                // 128
constexpr long kOffRs   = kOffTbc + kCI;                      // 1024
constexpr long kOffT    = kOffRs + kB * kC;                   // kB*kCI*kCI = 65536
constexpr long kOffBeta = kOffT + kB * kCI * kCI;             // 1024
constexpr long kOffPGW  = kOffBeta + kB * kC;                 // bf16: 256*256 ushorts
constexpr long kOffPG   = kOffPGW + (long)kC * kC / 2;        // bf16: kB*kC*kN ushorts
constexpr long kOffMtH  = kOffPG + (long)kB * kC * kN / 2;    // bf16: kB*kC*kC ushorts
constexpr long kOffXT   = kOffMtH + (long)kB * kC * kC / 2;   // bf16: kB*kN*kC ushorts

// ---- fused: xT transpose | centerw | T zero | PGW bf16 cast ---------------
// grid (64, 5, 4). y<4: xt tile. y==4: 256 blocks zero T + cast one weight
// row to bf16; first 4 also do centerw (+ tbc) + rs zero.
__global__ void __launch_bounds__(256, 4)
xt_fused(const float* __restrict__ x, ushort* __restrict__ xT,
         const float* __restrict__ theta_w, const float* __restrict__ theta_b,
         const float* __restrict__ phi_w, const float* __restrict__ g_w,
         float* __restrict__ twcT, float* __restrict__ tbc,
         float* __restrict__ rs, float* __restrict__ T,
         ushort* __restrict__ PGWh) {
    __shared__ __align__(16) float smem[128 * 65];  // union: Ls / ft
    int t = threadIdx.x;
    if (blockIdx.y == 4) {
        int idx = blockIdx.z * 64 + blockIdx.x;  // 0..255
        T[(long)idx * 256 + t] = 0.f;            // zero T (consumed by atomics)
        {   // PGWh row idx = bf16([phi_w; g_w][idx][:])
            const float* src = idx < kCI ? phi_w + (long)idx * kC
                                         : g_w + (long)(idx - kCI) * kC;
            if (t < 64) {
                float4 v = *(const float4*)(src + 4 * t);
                ushort4 u = {f2b(v.x), f2b(v.y), f2b(v.z), f2b(v.w)};
                *(ushort4*)(PGWh + (long)idx * kC + 4 * t) = u;
            }
        }
        if (idx >= 4) return;
        // ---- centerw for column block idx ----
        __shared__ float part[64][4];
        __shared__ float meanv[64];
        __shared__ float smr[128];
        float (*Ls)[65] = (float(*)[65])smem;
        int blk = idx, c0 = blk * 64;
        rs[blk * 256 + t] = 0.f;  // zero rs (consumed by pg's atomics)
#pragma unroll
        for (int it = 0; it < 8; it++) {  // stage theta_w[0:128][c0:c0+64]
            int l = t + 256 * it;
            int k = l >> 4, c4 = (l & 15) * 4;
            float4 v = *(const float4*)(theta_w + (long)k * kC + c0 + c4);
            Ls[k][c4 + 0] = v.x; Ls[k][c4 + 1] = v.y;
            Ls[k][c4 + 2] = v.z; Ls[k][c4 + 3] = v.w;
        }
        __syncthreads();
        {   // column means: 4 threads per column
            int c = t >> 2, q = t & 3;
            float s = 0.f;
#pragma unroll
            for (int k = 0; k < 32; k++) s += Ls[q * 32 + k][c];
            part[c][q] = s;
        }
        __syncthreads();
        if (t < 64)
            meanv[t] = (part[t][0] + part[t][1] + part[t][2] + part[t][3]) * (1.f / kCI);
        __syncthreads();
        {   // twcT[c][k] = theta_w[k][c] - mean[c]
            int c = t >> 2, ks = (t & 3) * 32;
            float* dst = twcT + (long)(c0 + c) * kCI + ks;
            float m = meanv[c];
#pragma unroll
            for (int k = 0; k < 32; k++) dst[k] = Ls[ks + k][c] - m;
        }
        if (blk == 0) {  // tbc = theta_b - mean(theta_b)
            if (t < 128) smr[t] = theta_b[t];
            __syncthreads();
            for (int st = 64; st > 0; st >>= 1) {
                if (t < st) smr[t] += smr[t + st];
                __syncthreads();
            }
            float bmean = smr[0] * (1.f / kCI);
            if (t < 128) tbc[t] = theta_b[t] - bmean;
        }
        return;
    }
    // ---- xt: xT[b][n][c] (bf16) = x[b][c][n] ----
    int b = blockIdx.z;
    int n0 = blockIdx.x * 64, c0 = blockIdx.y * 64;
    float (*ft)[66] = (float(*)[66])smem;  // 64*66 = 4224 floats
    const float* xb = x + (long)b * kC * kN;
#pragma unroll
    for (int i = 0; i < 4; i++) {
        int l = t + 256 * i;
        int row = l >> 4, col4 = (l & 15) * 4;  // row = c index, col = n
        float4 v = *(const float4*)(xb + (long)(c0 + row) * kN + n0 + col4);
        ft[row][col4 + 0] = v.x; ft[row][col4 + 1] = v.y;
        ft[row][col4 + 2] = v.z; ft[row][col4 + 3] = v.w;
    }
    __syncthreads();
    {   // write: thread t -> n-row (t>>2), 16-c segment ((t&3)*16)
        int n = t >> 2, cs = (t & 3) * 16;
        unsigned w[8];
#pragma unroll
        for (int j = 0; j < 8; j++) {
            ushort lo = f2b(ft[cs + 2 * j][n]);
            ushort hi = f2b(ft[cs + 2 * j + 1][n]);
            w[j] = (unsigned)lo | ((unsigned)hi << 16);
        }
        ushort* dst = xT + ((long)b * kN + n0 + n) * kC + c0 + cs;
        ((uint4*)dst)[0] = make_uint4(w[0], w[1], w[2], w[3]);
        ((uint4*)dst)[1] = make_uint4(w[4], w[5], w[6], w[7]);
    }
}

// ---- PG[b][r][n] (bf16) = PGW x X  via MFMA; rowsum fused -----------------
// 128(r) x 128(n) tile; 4 waves, each 32r x 128n = 2x8 MFMA tiles (16/chunk).
// W staging is a pure uint4 copy from pre-cast PGWh.
__global__ void __launch_bounds__(256, 2)
pg_mfma(const ushort* __restrict__ PGWh, const ushort* __restrict__ xT,
        ushort* __restrict__ PGh, float* __restrict__ rs) {
    int b = blockIdx.z;
    int r0 = blockIdx.y * 128, n0 = blockIdx.x * 128;
    __shared__ ushort Ws[128 * 40];  // [row][k] bf16, row stride 40 (80 B)
    __shared__ ushort Xs[128 * 40];
    int t = threadIdx.x;
    int w = t >> 6, lane = t & 63, q = lane >> 4, ln = lane & 15;
    f32x4 acc[2][8];
#pragma unroll
    for (int i = 0; i < 2; i++)
#pragma unroll
        for (int j = 0; j < 8; j++) acc[i][j] = 0.f;
    const ushort* xTb = xT + ((long)b * kN + n0) * kC;
    const ushort* Wb  = PGWh + (long)r0 * kC;
    for (int kc = 0; kc < kC; kc += 32) {
        __syncthreads();
#pragma unroll
        for (int it = 0; it < 2; it++) {  // W: 128 rows x 32 k (bf16 copy)
            int l = t + 256 * it;
            int row = l >> 2, seg = l & 3;
            *(uint4*)&Ws[row * 40 + seg * 8] =
                *(const uint4*)(Wb + (long)row * kC + kc + seg * 8);
        }
#pragma unroll
        for (int it = 0; it < 2; it++) {  // X: 128 rows x 32 k (bf16 copy)
            int l = t + 256 * it;
            int row = l >> 2, seg = l & 3;
            *(uint4*)&Xs[row * 40 + seg * 8] =
                *(const uint4*)(xTb + (long)row * kC + kc + seg * 8);
        }
        __syncthreads();
        bf16x8 a[2], bb[8];
#pragma unroll
        for (int mt = 0; mt < 2; mt++)
            a[mt] = *(const bf16x8*)&Ws[(32 * w + 16 * mt + ln) * 40 + q * 8];
#pragma unroll
        for (int nt = 0; nt < 8; nt++)
            bb[nt] = *(const bf16x8*)&Xs[(16 * nt + ln) * 40 + q * 8];
#pragma unroll
        for (int mt = 0; mt < 2; mt++)
#pragma unroll
            for (int nt = 0; nt < 8; nt++)
                acc[mt][nt] = __builtin_amdgcn_mfma_f32_16x16x32_bf16(
                    a[mt], bb[nt], acc[mt][nt], 0, 0, 0);
    }
    // store bf16 + accumulate row partials from the SAME quantized values
    ushort* pb = PGh + (long)b * kC * kN;
    float rpart[2][4] = {};
#pragma unroll
    for (int mt = 0; mt < 2; mt++)
#pragma unroll
        for (int nt = 0; nt < 8; nt++)
#pragma unroll
            for (int i = 0; i < 4; i++) {
                int row = r0 + 32 * w + 16 * mt + 4 * q + i;
                int col = n0 + 16 * nt + ln;
                ushort st = f2b(acc[mt][nt][i]);
                pb[(long)row * kN + col] = st;
                rpart[mt][i] += b2f(st);
            }
#pragma unroll
    for (int mt = 0; mt < 2; mt++)
#pragma unroll
        for (int i = 0; i < 4; i++) {
            float v = rpart[mt][i];
            v += __shfl_xor(v, 1);
            v += __shfl_xor(v, 2);
            v += __shfl_xor(v, 4);
            v += __shfl_xor(v, 8);
            if (ln == 0)
                atomicAdd(rs + b * kC + r0 + 32 * w + 16 * mt + 4 * q + i, v);
        }
}

// ---- T[b] += Phi[rows, slice] * G2[rows, slice]^T  (atomic accumulate) ----
// Rank-1 rowsum correction applied later in wm staging.
__global__ void __launch_bounds__(256, 4)
tsplit_mfma(const ushort* __restrict__ PGh, float* __restrict__ T) {
    int s = blockIdx.x, b = blockIdx.z;
    int qy = blockIdx.y >> 1, qx = blockIdx.y & 1;
    long nbase = (long)s * kSliceN;
    __shared__ ushort As[64 * 40];
    __shared__ ushort Bs[64 * 40];
    int t = threadIdx.x;
    int w = t >> 6, lane = t & 63, q = lane >> 4, ln = lane & 15;
    f32x4 acc[4];
#pragma unroll
    for (int j = 0; j < 4; j++) acc[j] = 0.f;
    const ushort* Phi = PGh + ((long)b * kC + 64 * qy) * kN + nbase;
    const ushort* G2  = PGh + ((long)b * kC + kCI + 64 * qx) * kN + nbase;
    for (int kc = 0; kc < kSliceN; kc += 32) {
        __syncthreads();
        {
            int row = t >> 2, seg = t & 3;
            *(uint4*)&As[row * 40 + seg * 8] =
                *(const uint4*)(Phi + (long)row * kN + kc + seg * 8);
            *(uint4*)&Bs[row * 40 + seg * 8] =
                *(const uint4*)(G2 + (long)row * kN + kc + seg * 8);
        }
        __syncthreads();
        bf16x8 a = *(const bf16x8*)&As[(16 * w + ln) * 40 + q * 8];
#pragma unroll
        for (int nt = 0; nt < 4; nt++) {
            bf16x8 bb = *(const bf16x8*)&Bs[(16 * nt + ln) * 40 + q * 8];
            acc[nt] = __builtin_amdgcn_mfma_f32_16x16x32_bf16(a, bb, acc[nt], 0, 0, 0);
        }
    }
    float* Tb = T + (long)b * kCI * kCI;
#pragma unroll
    for (int nt = 0; nt < 4; nt++)
#pragma unroll
        for (int i = 0; i < 4; i++) {
            int c  = 64 * qy + 16 * w + 4 * q + i;
            int cp = 64 * qx + 16 * nt + ln;
            atomicAdd(&Tb[(long)c * kCI + cp], acc[nt][i]);
        }
}

// ---- fused W2t + Mt + beta ------------------------------------------------
// Phase A: W2row[m][j] = sum_cp out_w[m0+m][cp] * (T[j][cp] - rank1) -> LDS.
// Phase B: Mt[m][n] (bf16) = sum_j W2row[m][j] * twcT[n0+n][j].
// beta[m] = out_b[m] + sum_j tbc[j]*W2row[m][j]  (blocks with n0==0).
__global__ void __launch_bounds__(256, 2)
wm_kernel(const float* __restrict__ out_w, const float* __restrict__ T,
          const float* __restrict__ rs, const float* __restrict__ twcT,
          const float* __restrict__ tbc, const float* __restrict__ out_b,
          ushort* __restrict__ Mth, float* __restrict__ beta) {
    int b = blockIdx.z;
    int m0 = blockIdx.y * 64, n0 = blockIdx.x * 64;
    const float* Tb = T + (long)b * kCI * kCI;
    __shared__ __align__(16) float As[16][68];    // 16 k x 64 stage (A / B2)
    __shared__ __align__(16) float Bs[16][132];   // 16 k x 128 stage (Tc rows)
    __shared__ __align__(16) float W2s[128][68];  // W2row^T: [j][m]
    int t = threadIdx.x;
    int tr = t >> 4, tc = t & 15;  // phase A: rows 4*tr.., cols 8*tc..
    float accA[4][8] = {};
    for (int c0 = 0; c0 < kCI; c0 += 16) {
        __syncthreads();
        {   // out_w[m0:m0+64][c0:c0+16] -> As[c][r]
            int r = t >> 2, c4 = (t & 3) * 4;
            float4 va = *(const float4*)(out_w + (long)(m0 + r) * kCI + c0 + c4);
            As[c4 + 0][r] = va.x; As[c4 + 1][r] = va.y;
            As[c4 + 2][r] = va.z; As[c4 + 3][r] = va.w;
        }
#pragma unroll
        for (int it = 0; it < 2; it++) {  // Tc[0:128][c0:c0+16] -> Bs[c][j]
            int l = t + 256 * it;
            int r = l >> 2, c4 = (l & 3) * 4;
            float4 vb = *(const float4*)(Tb + (long)r * kCI + c0 + c4);
            float rp = rs[b * kC + r] * (1.f / kN);
            const float* rg = rs + b * kC + kCI + c0 + c4;
            vb.x -= rp * rg[0]; vb.y -= rp * rg[1];
            vb.z -= rp * rg[2]; vb.w -= rp * rg[3];
            Bs[c4 + 0][r] = vb.x; Bs[c4 + 1][r] = vb.y;
            Bs[c4 + 2][r] = vb.z; Bs[c4 + 3][r] = vb.w;
        }
        __syncthreads();
#pragma unroll
        for (int k = 0; k < 16; k++) {
            float4 a = *(const float4*)&As[k][4 * tr];
            float4 b0 = *(const float4*)&Bs[k][8 * tc];
            float4 b1 = *(const float4*)&Bs[k][8 * tc + 4];
            float av[4] = {a.x, a.y, a.z, a.w};
            float bw[8] = {b0.x, b0.y, b0.z, b0.w, b1.x, b1.y, b1.z, b1.w};
#pragma unroll
            for (int i = 0; i < 4; i++)
#pragma unroll
                for (int j = 0; j < 8; j++) accA[i][j] += av[i] * bw[j];
        }
    }
    __syncthreads();
#pragma unroll
    for (int i = 0; i < 4; i++)
#pragma unroll
        for (int j = 0; j < 8; j++) W2s[8 * tc + j][4 * tr + i] = accA[i][j];
    __syncthreads();
    if (blockIdx.x == 0 && t < 64) {  // beta
        float s = out_b[m0 + t];
#pragma unroll 8
        for (int j = 0; j < kCI; j++) s += tbc[j] * W2s[j][t];
        beta[b * kC + m0 + t] = s;
    }
    // ---- phase B ----
    int ty = t >> 4, tx = t & 15;
    float accB[4][4] = {};
    for (int j0 = 0; j0 < kCI; j0 += 16) {
        __syncthreads();
        {   // twcT[n0:n0+64][j0:j0+16] -> As[j][n]  (reuse As)
            int r = t >> 2, c4 = (t & 3) * 4;
            float4 vb = *(const float4*)(twcT + (long)(n0 + r) * kCI + j0 + c4);
            As[c4 + 0][r] = vb.x; As[c4 + 1][r] = vb.y;
            As[c4 + 2][r] = vb.z; As[c4 + 3][r] = vb.w;
        }
        __syncthreads();
#pragma unroll
        for (int k = 0; k < 16; k++) {
            float4 a = *(const float4*)&W2s[j0 + k][4 * ty];
            float4 bv = *(const float4*)&As[k][4 * tx];
            float av[4] = {a.x, a.y, a.z, a.w};
            float bw[4] = {bv.x, bv.y, bv.z, bv.w};
#pragma unroll
            for (int i = 0; i < 4; i++)
#pragma unroll
                for (int j = 0; j < 4; j++) accB[i][j] += av[i] * bw[j];
        }
    }
    ushort* Cb = Mth + (long)b * kC * kC;
#pragma unroll
    for (int i = 0; i < 4; i++) {
        ushort4 u = {f2b(accB[i][0]), f2b(accB[i][1]), f2b(accB[i][2]), f2b(accB[i][3])};
        *(ushort4*)(Cb + (long)(m0 + 4 * ty + i) * kC + n0 + 4 * tx) = u;
    }
}

// ---- out = x + Mt(bf16) x X(bf16) + beta  via MFMA ------------------------
// 128(o) x 128(n) tile; residual from fp32 x (coalesced: col = ln-contig).
__global__ void __launch_bounds__(256, 2)
final_mfma(const float* __restrict__ x, const ushort* __restrict__ Mth,
           const ushort* __restrict__ xT, const float* __restrict__ beta,
           float* __restrict__ out) {
    int b = blockIdx.z;
    int o0 = blockIdx.y * 128, n0 = blockIdx.x * 128;
    const ushort* Mbh = Mth + (long)b * kC * kC;
    __shared__ ushort Ws[128 * 40];
    __shared__ ushort Xs[128 * 40];
    int t = threadIdx.x;
    int w = t >> 6, lane = t & 63, q = lane >> 4, ln = lane & 15;
    f32x4 acc[2][8];
#pragma unroll
    for (int i = 0; i < 2; i++)
#pragma unroll
        for (int j = 0; j < 8; j++) acc[i][j] = 0.f;
    const ushort* xTb = xT + ((long)b * kN + n0) * kC;
    for (int kc = 0; kc < kC; kc += 32) {
        __syncthreads();
#pragma unroll
        for (int it = 0; it < 2; it++) {  // Mt: 128 rows x 32 k (bf16 copy)
            int l = t + 256 * it;
            int row = l >> 2, seg = l & 3;
            uint4 v = *(const uint4*)(Mbh + (long)(o0 + row) * kC + kc + seg * 8);
            *(uint4*)&Ws[row * 40 + seg * 8] = v;
        }
#pragma unroll
        for (int it = 0; it < 2; it++) {  // X: 128 rows x 32 k (bf16 copy)
            int l = t + 256 * it;
            int row = l >> 2, seg = l & 3;
            uint4 v = *(const uint4*)(xTb + (long)row * kC + kc + seg * 8);
            *(uint4*)&Xs[row * 40 + seg * 8] = v;
        }
        __syncthreads();
        bf16x8 a[2], bb[8];
#pragma unroll
        for (int mt = 0; mt < 2; mt++)
            a[mt] = *(const bf16x8*)&Ws[(32 * w + 16 * mt + ln) * 40 + q * 8];
#pragma unroll
        for (int nt = 0; nt < 8; nt++)
            bb[nt] = *(const bf16x8*)&Xs[(16 * nt + ln) * 40 + q * 8];
#pragma unroll
        for (int mt = 0; mt < 2; mt++)
#pragma unroll
            for (int nt = 0; nt < 8; nt++)
                acc[mt][nt] = __builtin_amdgcn_mfma_f32_16x16x32_bf16(
                    a[mt], bb[nt], acc[mt][nt], 0, 0, 0);
    }
    const float* xb = x + (long)b * kC * kN;
    float* ob = out + (long)b * kC * kN;
#pragma unroll
    for (int mt = 0; mt < 2; mt++)
#pragma unroll
        for (int nt = 0; nt < 8; nt++)
#pragma unroll
            for (int i = 0; i < 4; i++) {
                int row = o0 + 32 * w + 16 * mt + 4 * q + i;
                int col = n0 + 16 * nt + ln;
                long idx = (long)row * kN + col;
                ob[idx] = acc[mt][nt][i] + xb[idx] + beta[b * kC + row];
            }
}

extern "C" void kernel_launch(void* const* d_in, const int* in_sizes, int n_in,
                              void* d_out, int out_size, void* d_ws, size_t ws_size,
                              hipStream_t stream) {
    const float* x       = (const float*)d_in[0];
    const float* g_w     = (const float*)d_in[1];
    // d_in[2] = g_b   : cancelled (rows of Phic sum to 0)
    const float* theta_w = (const float*)d_in[3];
    const float* theta_b = (const float*)d_in[4];
    const float* phi_w   = (const float*)d_in[5];
    // d_in[6] = phi_b : cancelled by spatial centering
    const float* out_w   = (const float*)d_in[7];
    const float* out_b   = (const float*)d_in[8];
    float* out = (float*)d_out;
    float* ws  = (float*)d_ws;  // needs ~27 MB

    float*  twcT = ws + kOffTwcT;
    float*  tbc  = ws + kOffTbc;
    float*  rs   = ws + kOffRs;
    float*  T    = ws + kOffT;
    float*  beta = ws + kOffBeta;
    ushort* PGWh = (ushort*)(ws + kOffPGW);
    ushort* PGh  = (ushort*)(ws + kOffPG);
    ushort* Mth  = (ushort*)(ws + kOffMtH);
    ushort* xT   = (ushort*)(ws + kOffXT);

    // xT + centerw (twcT/tbc, rs zero) + T zero + PGW bf16 cast, one launch
    xt_fused<<<dim3(kN / 64, 5, kB), 256, 0, stream>>>(
        x, xT, theta_w, theta_b, phi_w, g_w, twcT, tbc, rs, T, PGWh);
    // PG[b] = PGW * X[b]   (MFMA bf16 in/out; rowsum fused)
    pg_mfma<<<dim3(kN / 128, 2, kB), 256, 0, stream>>>(PGWh, xT, PGh, rs);
    // T[b] += Phi_slice * G2_slice^T   (atomic accumulate)
    tsplit_mfma<<<dim3(kSplits, 4, kB), 256, 0, stream>>>(PGh, T);
    // W2t (LDS) -> Mt (bf16) + beta, one kernel
    wm_kernel<<<dim3(4, 4, kB), 256, 0, stream>>>(out_w, T, rs, twcT, tbc,
                                                  out_b, Mth, beta);
    // out = x + Mt * X + beta       (fp32 residual, coalesced)
    final_mfma<<<dim3(kN / 128, 2, kB), 256, 0, stream>>>(x, Mth, xT, beta, out);
}